// Round 1
// baseline (809.305 us; speedup 1.0000x reference)
//
#include <hip/hip_runtime.h>
#include <hip/hip_bf16.h>
#include <stdint.h>

// Problem constants (static equal expert split per reference)
#define TOKENS 16384
#define HIDDEN 2048
#define FFN    1408
#define NEXP   8
#define TPE    (TOKENS / NEXP)   // 2048 tokens per expert

typedef __attribute__((ext_vector_type(8))) short bf16x8;   // 8 bf16 = 4 VGPR (MFMA A/B frag)
typedef __attribute__((ext_vector_type(4))) float f32x4;    // MFMA C/D frag

__device__ inline unsigned short f2bf(float f) {
    // round-to-nearest-even f32 -> bf16
    union { float f; unsigned u; } v; v.f = f;
    unsigned u = v.u;
    u += 0x7fffu + ((u >> 16) & 1u);
    return (unsigned short)(u >> 16);
}

// ---------------- cast x: f32 [16384,2048] -> bf16 linear ----------------
__global__ void cast_x_kernel(const float* __restrict__ in, unsigned short* __restrict__ out) {
    size_t i = (size_t)blockIdx.x * blockDim.x + threadIdx.x;  // 8 floats per thread
    const float4* p = (const float4*)in;
    float4 v0 = p[2 * i];
    float4 v1 = p[2 * i + 1];
    bf16x8 o;
    o[0] = (short)f2bf(v0.x); o[1] = (short)f2bf(v0.y);
    o[2] = (short)f2bf(v0.z); o[3] = (short)f2bf(v0.w);
    o[4] = (short)f2bf(v1.x); o[5] = (short)f2bf(v1.y);
    o[6] = (short)f2bf(v1.z); o[7] = (short)f2bf(v1.w);
    *(bf16x8*)&out[8 * i] = o;
}

// ------- transpose-cast: per expert f32 [R][C] -> bf16 [C][R] (B^T layout) -------
__global__ void transpose_cast_kernel(const float* __restrict__ in, unsigned short* __restrict__ out,
                                      int R, int C) {
    __shared__ float tile[64][65];   // +1 pad: conflict-free both phases
    const int e = blockIdx.z;
    const float* src = in + (size_t)e * R * C;
    unsigned short* dst = out + (size_t)e * R * C;
    const int tx = threadIdx.x & 63;
    const int ty = threadIdx.x >> 6;           // 4 rows per pass
    const int r0 = blockIdx.y * 64, c0 = blockIdx.x * 64;
#pragma unroll
    for (int p = 0; p < 16; ++p) {
        int r = p * 4 + ty;
        tile[r][tx] = src[(size_t)(r0 + r) * C + (c0 + tx)];
    }
    __syncthreads();
#pragma unroll
    for (int p = 0; p < 16; ++p) {
        int r = p * 4 + ty;
        dst[(size_t)(c0 + r) * R + (r0 + tx)] = f2bf(tile[tx][r]);
    }
}

// ---------------- GEMM tile geometry (m97 structure: 128x128, BK=32, 4 waves) ----------------
#define BM 128
#define BN 128
#define BK 32

#define GLOAD_LDS16(g, l)                                                              \
    __builtin_amdgcn_global_load_lds((const __attribute__((address_space(1))) void*)(g), \
                                     (__attribute__((address_space(3))) void*)(l), 16, 0, 0)

// GEMM1 + SwiGLU fused:
// inter_a = X @ W1[:, :F], inter_b = X @ W1[:, F:]  (W1T rows n and F+n)
// ACT = silu(inter_a) * inter_b  (bf16)
__global__ __launch_bounds__(256, 2) void moe_gemm1_swiglu(
        const unsigned short* __restrict__ X,    // [TOKENS][HIDDEN] bf16
        const unsigned short* __restrict__ W1T,  // [E][2F][HIDDEN] bf16 (pre-transposed)
        unsigned short* __restrict__ ACT)        // [TOKENS][FFN] bf16
{
    const int e  = blockIdx.z;
    const int m0 = blockIdx.x * BM;
    const int n0 = blockIdx.y * BN;
    const int tid  = threadIdx.x;
    const int lane = tid & 63;
    const int w    = tid >> 6;
    const int wr = w >> 1, wc = w & 1;   // 64x64 quadrant per wave

    __shared__ __align__(16) unsigned short sA [BM * BK];
    __shared__ __align__(16) unsigned short sBa[BN * BK];
    __shared__ __align__(16) unsigned short sBb[BN * BK];
    char* sAc  = (char*)sA;
    char* sBac = (char*)sBa;
    char* sBbc = (char*)sBb;

    const unsigned short* Ag  = X   + ((size_t)e * TPE + m0) * HIDDEN;
    const unsigned short* Bag = W1T + ((size_t)e * (2 * FFN) + n0) * HIDDEN;
    const unsigned short* Bbg = W1T + ((size_t)e * (2 * FFN) + FFN + n0) * HIDDEN;

    f32x4 acc_a[4][4] = {};
    f32x4 acc_b[4][4] = {};

    // staging chunk map: chunk c = tid + iss*256; row=c>>2, kchunk=c&3 (16B each);
    // LDS fill is linear (required by global_load_lds), dest base wave-uniform.
    const int crow = tid >> 2;
    const int kc8  = (tid & 3) * 8;
    const int ldsb0 = w * 1024;
    const int ldsb1 = w * 1024 + 4096;

    for (int kt = 0; kt < HIDDEN / BK; ++kt) {
        const int k0 = kt * BK;
        __syncthreads();   // previous iter's frags consumed before overwrite
        {
            const unsigned short* g = Ag + (size_t)crow * HIDDEN + k0 + kc8;
            GLOAD_LDS16(g, sAc + ldsb0);
            GLOAD_LDS16(g + (size_t)64 * HIDDEN, sAc + ldsb1);
        }
        {
            const unsigned short* g = Bag + (size_t)crow * HIDDEN + k0 + kc8;
            GLOAD_LDS16(g, sBac + ldsb0);
            GLOAD_LDS16(g + (size_t)64 * HIDDEN, sBac + ldsb1);
        }
        {
            const unsigned short* g = Bbg + (size_t)crow * HIDDEN + k0 + kc8;
            GLOAD_LDS16(g, sBbc + ldsb0);
            GLOAD_LDS16(g + (size_t)64 * HIDDEN, sBbc + ldsb1);
        }
        __syncthreads();   // drains vmcnt before any wave reads the tiles

        const int rrow = lane & 15;
        const int kb   = (lane >> 4) * 16;   // byte offset of this lane's 8-elem k-slice
        bf16x8 af[4], baf[4], bbf[4];
#pragma unroll
        for (int i = 0; i < 4; ++i)
            af[i] = *(const bf16x8*)(sAc + (wr * 64 + i * 16 + rrow) * (BK * 2) + kb);
#pragma unroll
        for (int j = 0; j < 4; ++j) {
            baf[j] = *(const bf16x8*)(sBac + (wc * 64 + j * 16 + rrow) * (BK * 2) + kb);
            bbf[j] = *(const bf16x8*)(sBbc + (wc * 64 + j * 16 + rrow) * (BK * 2) + kb);
        }
#pragma unroll
        for (int i = 0; i < 4; ++i)
#pragma unroll
            for (int j = 0; j < 4; ++j) {
                acc_a[i][j] = __builtin_amdgcn_mfma_f32_16x16x32_bf16(af[i], baf[j], acc_a[i][j], 0, 0, 0);
                acc_b[i][j] = __builtin_amdgcn_mfma_f32_16x16x32_bf16(af[i], bbf[j], acc_b[i][j], 0, 0, 0);
            }
    }

    // epilogue: silu(a)*b -> bf16 ACT. C/D layout: col=lane&15, row=(lane>>4)*4+r (m89-verified)
    const int rg   = lane >> 4;
    const int ccol = lane & 15;
    const size_t rowbase = (size_t)e * TPE + m0 + wr * 64;
#pragma unroll
    for (int i = 0; i < 4; ++i)
#pragma unroll
        for (int j = 0; j < 4; ++j)
#pragma unroll
            for (int r = 0; r < 4; ++r) {
                int row = i * 16 + rg * 4 + r;
                int col = n0 + wc * 64 + j * 16 + ccol;
                float a = acc_a[i][j][r];
                float b = acc_b[i][j][r];
                float s = (a / (1.0f + __expf(-a))) * b;
                ACT[(rowbase + row) * FFN + col] = f2bf(s);
            }
}

// GEMM2: OUT = ACT @ W2   (W2T pre-transposed to [E][HIDDEN][FFN])
__global__ __launch_bounds__(256, 2) void moe_gemm2(
        const unsigned short* __restrict__ ACT,  // [TOKENS][FFN] bf16
        const unsigned short* __restrict__ W2T,  // [E][HIDDEN][FFN] bf16
        float* __restrict__ OUT)                 // [TOKENS][HIDDEN] f32
{
    const int e  = blockIdx.z;
    const int m0 = blockIdx.x * BM;
    const int n0 = blockIdx.y * BN;
    const int tid  = threadIdx.x;
    const int lane = tid & 63;
    const int w    = tid >> 6;
    const int wr = w >> 1, wc = w & 1;

    __shared__ __align__(16) unsigned short sA[BM * BK];
    __shared__ __align__(16) unsigned short sB[BN * BK];
    char* sAc = (char*)sA;
    char* sBc = (char*)sB;

    const unsigned short* Ag = ACT + ((size_t)e * TPE + m0) * FFN;
    const unsigned short* Bg = W2T + ((size_t)e * HIDDEN + n0) * FFN;

    f32x4 acc[4][4] = {};

    const int crow = tid >> 2;
    const int kc8  = (tid & 3) * 8;
    const int ldsb0 = w * 1024;
    const int ldsb1 = w * 1024 + 4096;

    for (int kt = 0; kt < FFN / BK; ++kt) {   // 44 iterations
        const int k0 = kt * BK;
        __syncthreads();
        {
            const unsigned short* g = Ag + (size_t)crow * FFN + k0 + kc8;
            GLOAD_LDS16(g, sAc + ldsb0);
            GLOAD_LDS16(g + (size_t)64 * FFN, sAc + ldsb1);
        }
        {
            const unsigned short* g = Bg + (size_t)crow * FFN + k0 + kc8;
            GLOAD_LDS16(g, sBc + ldsb0);
            GLOAD_LDS16(g + (size_t)64 * FFN, sBc + ldsb1);
        }
        __syncthreads();

        const int rrow = lane & 15;
        const int kb   = (lane >> 4) * 16;
        bf16x8 af[4], bf[4];
#pragma unroll
        for (int i = 0; i < 4; ++i)
            af[i] = *(const bf16x8*)(sAc + (wr * 64 + i * 16 + rrow) * (BK * 2) + kb);
#pragma unroll
        for (int j = 0; j < 4; ++j)
            bf[j] = *(const bf16x8*)(sBc + (wc * 64 + j * 16 + rrow) * (BK * 2) + kb);
#pragma unroll
        for (int i = 0; i < 4; ++i)
#pragma unroll
            for (int j = 0; j < 4; ++j)
                acc[i][j] = __builtin_amdgcn_mfma_f32_16x16x32_bf16(af[i], bf[j], acc[i][j], 0, 0, 0);
    }

    const int rg   = lane >> 4;
    const int ccol = lane & 15;
    const size_t rowbase = (size_t)e * TPE + m0 + wr * 64;
#pragma unroll
    for (int i = 0; i < 4; ++i)
#pragma unroll
        for (int j = 0; j < 4; ++j)
#pragma unroll
            for (int r = 0; r < 4; ++r) {
                int row = i * 16 + rg * 4 + r;
                int col = n0 + wc * 64 + j * 16 + ccol;
                OUT[(rowbase + row) * HIDDEN + col] = acc[i][j][r];
            }
}

// ---------------- launch ----------------
extern "C" void kernel_launch(void* const* d_in, const int* in_sizes, int n_in,
                              void* d_out, int out_size, void* d_ws, size_t ws_size,
                              hipStream_t stream) {
    const float* x  = (const float*)d_in[0];
    // d_in[1]: num_tokens_per_expert (int64) — static equal split, unused
    const float* w1 = (const float*)d_in[2];   // [E][HIDDEN][2F] f32
    const float* w2 = (const float*)d_in[3];   // [E][FFN][HIDDEN] f32
    float* out = (float*)d_out;

    // workspace layout (bf16):
    //   xb  : TOKENS*HIDDEN            = 64 MB   @ 0
    //   w1T : E*2F*HIDDEN              = 88 MB   @ 64 MB
    //   w2T : E*HIDDEN*FFN             = 44 MB   @ 152 MB
    //   act : TOKENS*FFN               = 44 MB   @ 196 MB   (total 240 MB)
    char* ws = (char*)d_ws;
    unsigned short* xb  = (unsigned short*)(ws);
    unsigned short* w1T = (unsigned short*)(ws + 67108864);
    unsigned short* w2T = (unsigned short*)(ws + 159383552);
    unsigned short* act = (unsigned short*)(ws + 205520896);

    // 1) casts / transposes to bf16 B^T layouts
    cast_x_kernel<<<dim3((TOKENS * HIDDEN) / (256 * 8)), 256, 0, stream>>>(x, xb);
    transpose_cast_kernel<<<dim3((2 * FFN) / 64, HIDDEN / 64, NEXP), 256, 0, stream>>>(w1, w1T, HIDDEN, 2 * FFN);
    transpose_cast_kernel<<<dim3(HIDDEN / 64, FFN / 64, NEXP), 256, 0, stream>>>(w2, w2T, FFN, HIDDEN);

    // 2) fused GEMM1 + swiglu -> bf16 act
    moe_gemm1_swiglu<<<dim3(TPE / BM, FFN / BN, NEXP), 256, 0, stream>>>(xb, w1T, act);

    // 3) GEMM2 -> f32 out
    moe_gemm2<<<dim3(TPE / BM, HIDDEN / BN, NEXP), 256, 0, stream>>>(act, w2T, out);
}

// Round 4
// 724.341 us; speedup vs baseline: 1.1173x; 1.1173x over previous
//
#include <hip/hip_runtime.h>
#include <hip/hip_bf16.h>
#include <stdint.h>

#define TOKENS 16384
#define HIDDEN 2048
#define FFN    1408
#define NEXP   8
#define TPE    (TOKENS / NEXP)   // 2048 tokens per expert

typedef __attribute__((ext_vector_type(8))) short bf16x8;
typedef __attribute__((ext_vector_type(4))) float f32x4;

__device__ inline unsigned short f2bf(float f) {
    union { float f; unsigned u; } v; v.f = f;
    unsigned u = v.u;
    u += 0x7fffu + ((u >> 16) & 1u);
    return (unsigned short)(u >> 16);
}
__device__ inline float bf2f(unsigned short u) {
    union { unsigned u; float f; } v; v.u = ((unsigned)u) << 16; return v.f;
}

// ---------------- cast x: f32 -> bf16 linear ----------------
__global__ void cast_x_kernel(const float* __restrict__ in, unsigned short* __restrict__ out) {
    size_t i = (size_t)blockIdx.x * blockDim.x + threadIdx.x;
    const float4* p = (const float4*)in;
    float4 v0 = p[2 * i];
    float4 v1 = p[2 * i + 1];
    bf16x8 o;
    o[0] = (short)f2bf(v0.x); o[1] = (short)f2bf(v0.y);
    o[2] = (short)f2bf(v0.z); o[3] = (short)f2bf(v0.w);
    o[4] = (short)f2bf(v1.x); o[5] = (short)f2bf(v1.y);
    o[6] = (short)f2bf(v1.z); o[7] = (short)f2bf(v1.w);
    *(bf16x8*)&out[8 * i] = o;
}

// ------- transpose-cast: per expert f32 [R][C] -> bf16 [C][R] -------
__global__ void transpose_cast_kernel(const float* __restrict__ in, unsigned short* __restrict__ out,
                                      int R, int C) {
    __shared__ float tile[64][65];
    const int e = blockIdx.z;
    const float* src = in + (size_t)e * R * C;
    unsigned short* dst = out + (size_t)e * R * C;
    const int tx = threadIdx.x & 63;
    const int ty = threadIdx.x >> 6;
    const int r0 = blockIdx.y * 64, c0 = blockIdx.x * 64;
#pragma unroll
    for (int p = 0; p < 16; ++p) {
        int r = p * 4 + ty;
        tile[r][tx] = src[(size_t)(r0 + r) * C + (c0 + tx)];
    }
    __syncthreads();
#pragma unroll
    for (int p = 0; p < 16; ++p) {
        int r = p * 4 + ty;
        dst[(size_t)(c0 + r) * R + (r0 + tx)] = f2bf(tile[tx][r]);
    }
}

// ---------------- swiglu: inter [T][2816] -> act [T][1408] bf16 ----------------
__global__ void swiglu_kernel(const unsigned short* __restrict__ inter, unsigned short* __restrict__ act) {
    int i = blockIdx.x * 256 + threadIdx.x;       // one bf16x8 output
    int t = i / (FFN / 8);
    int f = (i % (FFN / 8)) * 8;
    bf16x8 a8 = *(const bf16x8*)&inter[(size_t)t * (2 * FFN) + f];
    bf16x8 b8 = *(const bf16x8*)&inter[(size_t)t * (2 * FFN) + FFN + f];
    bf16x8 o;
#pragma unroll
    for (int j = 0; j < 8; ++j) {
        float a = bf2f((unsigned short)a8[j]);
        float b = bf2f((unsigned short)b8[j]);
        float s = (a / (1.0f + __expf(-a))) * b;
        o[j] = (short)f2bf(s);
    }
    *(bf16x8*)&act[(size_t)t * FFN + f] = o;
}

// ---------------- 256x256 8-phase GEMM (BK=64, 8 waves, dbuf+swizzle+counted vmcnt) ----------------
__device__ inline void store_c(float* p, float v) { *p = v; }
__device__ inline void store_c(unsigned short* p, float v) { *p = f2bf(v); }

#define GLOAD_LDS16(g, l)                                                              \
    __builtin_amdgcn_global_load_lds((const __attribute__((address_space(1))) void*)(g), \
                                     (__attribute__((address_space(3))) void*)(l), 16, 0, 0)

#define BAR()    __builtin_amdgcn_s_barrier()
#define CFENCE() asm volatile("" ::: "memory")
#define LGKM0()  asm volatile("s_waitcnt lgkmcnt(0)" ::: "memory")
#define VMC4()   asm volatile("s_waitcnt vmcnt(4)" ::: "memory")
#define VMC0()   asm volatile("s_waitcnt vmcnt(0)" ::: "memory")

// stage one 128x64 half-tile: linear LDS dest, inverse-swizzled global source (rule #21)
#define STAGE(slot_, op_, half_, tk_) do {                                              \
    const unsigned short* gb_ = ((op_) ? Bg : Ag)                                       \
        + (size_t)((half_) * 128 + srow) * K + (tk_) * 64 + scol;                       \
    char* db_ = L + (slot_) * 65536 + (op_) * 32768 + (half_) * 16384 + (w << 10);      \
    GLOAD_LDS16(gb_, db_);                                                              \
    GLOAD_LDS16(gb_ + (size_t)64 * K, db_ + 8192);                                      \
  } while (0)

// load 4 A-frags (x2 k-substeps) from slot/half, swizzled read
#define LOAD_A(slot_, mh_) do {                                                         \
    const char* Ab_ = L + (slot_) * 65536 + (mh_) * 16384 + aoff;                       \
    af[0][0] = *(const bf16x8*)(Ab_ + colb0);        af[0][1] = *(const bf16x8*)(Ab_ + colb1); \
    af[1][0] = *(const bf16x8*)(Ab_ + 2048 + colb0); af[1][1] = *(const bf16x8*)(Ab_ + 2048 + colb1); \
    af[2][0] = *(const bf16x8*)(Ab_ + 4096 + colb0); af[2][1] = *(const bf16x8*)(Ab_ + 4096 + colb1); \
    af[3][0] = *(const bf16x8*)(Ab_ + 6144 + colb0); af[3][1] = *(const bf16x8*)(Ab_ + 6144 + colb1); \
  } while (0)

#define LOAD_B(slot_, nh_) do {                                                         \
    const char* Bb_ = L + (slot_) * 65536 + 32768 + (nh_) * 16384 + boff;               \
    bfr[(nh_)*2][0]   = *(const bf16x8*)(Bb_ + colb0);        bfr[(nh_)*2][1]   = *(const bf16x8*)(Bb_ + colb1); \
    bfr[(nh_)*2+1][0] = *(const bf16x8*)(Bb_ + 2048 + colb0); bfr[(nh_)*2+1][1] = *(const bf16x8*)(Bb_ + 2048 + colb1); \
  } while (0)

#define MFMA_Q(mh_, nh_) do {                                                           \
    _Pragma("unroll")                                                                   \
    for (int kk2 = 0; kk2 < 2; ++kk2)                                                   \
    _Pragma("unroll")                                                                   \
    for (int mm = 0; mm < 4; ++mm)                                                      \
    _Pragma("unroll")                                                                   \
    for (int nn = 0; nn < 2; ++nn)                                                      \
        acc[(mh_)*4+mm][(nh_)*2+nn] = __builtin_amdgcn_mfma_f32_16x16x32_bf16(          \
            af[mm][kk2], bfr[(nh_)*2+nn][kk2], acc[(mh_)*4+mm][(nh_)*2+nn], 0, 0, 0);   \
  } while (0)

#define PRIO1() __builtin_amdgcn_s_setprio(1)
#define PRIO0() __builtin_amdgcn_s_setprio(0)

// A: [E*2048][K] bf16 row-major. B: [E*NBLK*256][K] bf16 (B^T). C: [E*2048][NCOLS].
template <int K, int NCOLS, int NBLK, typename OutT>
__global__ __launch_bounds__(512, 2) void gemm8p(
        const unsigned short* __restrict__ Abase,
        const unsigned short* __restrict__ Bbase,
        OutT* __restrict__ Cbase)
{
    constexpr int NT = K / 64;        // K-tiles (even for K=2048, 1408)
    constexpr int NITER = NT / 2;

    // XCD-aware swizzle: nwg = 8*8*NBLK (%8==0); expert == XCD, mb fastest.
    const int bid = blockIdx.x;
    const int e   = bid & 7;
    const int rem = bid >> 3;
    const int nb  = rem >> 3;
    const int mb  = rem & 7;
    const int m0 = mb * 256, n0 = nb * 256;

    const unsigned short* Ag = Abase + ((size_t)e * 2048 + m0) * K;
    const unsigned short* Bg = Bbase + ((size_t)e * (NBLK * 256) + n0) * K;

    const int tid = threadIdx.x, lane = tid & 63, w = tid >> 6;
    const int wr = w >> 2, wc = w & 3;   // 2 x 4 wave grid; wave owns 128x64 (split rows/cols)

    __shared__ __align__(16) unsigned short lds[2][2][2][8192]; // [slot][A/B][half][128*64]
    char* L = (char*)lds;

    // staging source constants (inverse swizzle baked in)
    const int srow = (w << 3) + (lane >> 3);
    const int scol = ((lane & 7) ^ (lane >> 3)) << 3;   // elems

    // fragment read constants (swizzled)
    const int arow = lane & 15;
    const int colb0 = (((lane >> 4) << 4)) ^ ((lane & 7) << 4);
    const int colb1 = (64 | ((lane >> 4) << 4)) ^ ((lane & 7) << 4);
    const int aoff = (wr * 64 + arow) * 128;
    const int boff = (wc * 32 + arow) * 128;

    f32x4 acc[8][4] = {};
    bf16x8 af[4][2], bfr[4][2];

    // prologue: tile0 (all 4 halves) + tile1 A0,B0; drain tile0 (vmcnt 4)
    STAGE(0, 0, 0, 0); STAGE(0, 1, 0, 0);
    STAGE(0, 0, 1, 0); STAGE(0, 1, 1, 0);
    STAGE(1, 0, 0, 1); STAGE(1, 1, 0, 1);
    VMC4();
    BAR(); CFENCE();

    for (int it = 0; it < NITER; ++it) {
        const int t = 2 * it;
        const bool more = (it + 1) < NITER;

        // ---- phase 1: tile t quad(0,0) ----
        LOAD_A(0, 0); LOAD_B(0, 0);
        STAGE(1, 0, 1, t + 1);
        BAR(); CFENCE(); LGKM0();
        PRIO1(); MFMA_Q(0, 0); PRIO0();
        BAR(); CFENCE();
        // ---- phase 2: quad(0,1) ----
        LOAD_B(0, 1);
        STAGE(1, 1, 1, t + 1);
        BAR(); CFENCE(); LGKM0();
        PRIO1(); MFMA_Q(0, 1); PRIO0();
        BAR(); CFENCE();
        // ---- phase 3: quad(1,0) ----
        LOAD_A(0, 1);
        if (more) STAGE(0, 0, 0, t + 2);
        BAR(); CFENCE(); LGKM0();
        PRIO1(); MFMA_Q(1, 0); PRIO0();
        BAR(); CFENCE();
        // ---- phase 4: quad(1,1); publish tile t+1 ----
        if (more) STAGE(0, 1, 0, t + 2);
        BAR(); CFENCE();
        PRIO1(); MFMA_Q(1, 1); PRIO0();
        if (more) VMC4(); else VMC0();
        BAR(); CFENCE();
        // ---- phase 5: tile t+1 quad(0,0) ----
        LOAD_A(1, 0); LOAD_B(1, 0);
        if (more) STAGE(0, 0, 1, t + 2);
        BAR(); CFENCE(); LGKM0();
        PRIO1(); MFMA_Q(0, 0); PRIO0();
        BAR(); CFENCE();
        // ---- phase 6: quad(0,1) ----
        LOAD_B(1, 1);
        if (more) STAGE(0, 1, 1, t + 2);
        BAR(); CFENCE(); LGKM0();
        PRIO1(); MFMA_Q(0, 1); PRIO0();
        BAR(); CFENCE();
        // ---- phase 7: quad(1,0) ----
        LOAD_A(1, 1);
        if (more) STAGE(1, 0, 0, t + 3);
        BAR(); CFENCE(); LGKM0();
        PRIO1(); MFMA_Q(1, 0); PRIO0();
        BAR(); CFENCE();
        // ---- phase 8: quad(1,1); publish tile t+2 ----
        if (more) STAGE(1, 1, 0, t + 3);
        BAR(); CFENCE();
        PRIO1(); MFMA_Q(1, 1); PRIO0();
        if (more) VMC4(); else VMC0();
        BAR(); CFENCE();
    }

    // epilogue: C/D layout col=lane&15, row=(lane>>4)*4+r (m89-verified)
    OutT* Cg = Cbase + ((size_t)e * 2048 + m0) * NCOLS + n0;
#pragma unroll
    for (int m = 0; m < 8; ++m) {
        const int rbase = (m >> 2) * 128 + wr * 64 + (m & 3) * 16 + (lane >> 4) * 4;
#pragma unroll
        for (int n = 0; n < 4; ++n) {
            const int c = (n >> 1) * 128 + wc * 32 + (n & 1) * 16 + (lane & 15);
#pragma unroll
            for (int r = 0; r < 4; ++r)
                store_c(&Cg[(size_t)(rbase + r) * NCOLS + c], acc[m][n][r]);
        }
    }
}

// ---------------- launch ----------------
extern "C" void kernel_launch(void* const* d_in, const int* in_sizes, int n_in,
                              void* d_out, int out_size, void* d_ws, size_t ws_size,
                              hipStream_t stream) {
    const float* x  = (const float*)d_in[0];
    const float* w1 = (const float*)d_in[2];   // [E][HIDDEN][2F] f32
    const float* w2 = (const float*)d_in[3];   // [E][FFN][HIDDEN] f32
    float* out = (float*)d_out;

    // ws layout (bytes):
    //   xb    @ 0          : 67,108,864  (bf16 [T][H])        -- act aliases this after gemm1
    //   w1T   @ 67108864   : 92,274,688  (bf16 [E][2F][H])
    //   w2T   @ 159383552  : 46,137,344  (bf16 [E][H][F])
    //   inter @ 205520896  : 92,274,688  (bf16 [T][2F])       high-water ~284 MiB
    char* ws = (char*)d_ws;
    unsigned short* xb    = (unsigned short*)(ws);
    unsigned short* w1T   = (unsigned short*)(ws + 67108864);
    unsigned short* w2T   = (unsigned short*)(ws + 159383552);
    unsigned short* inter = (unsigned short*)(ws + 205520896);
    unsigned short* act   = (unsigned short*)(ws);   // alias xb: gemm1 done before swiglu writes

    cast_x_kernel<<<dim3((TOKENS * HIDDEN) / (256 * 8)), 256, 0, stream>>>(x, xb);
    transpose_cast_kernel<<<dim3((2 * FFN) / 64, HIDDEN / 64, NEXP), 256, 0, stream>>>(w1, w1T, HIDDEN, 2 * FFN);
    transpose_cast_kernel<<<dim3(HIDDEN / 64, FFN / 64, NEXP), 256, 0, stream>>>(w2, w2T, FFN, HIDDEN);

    // GEMM1: [T,H] x [2F,H]^T -> inter [T,2F]   (M=2048/exp, N=2816, K=2048)
    gemm8p<HIDDEN, 2 * FFN, 11, unsigned short><<<8 * 8 * 11, 512, 0, stream>>>(xb, w1T, inter);
    // swiglu -> act [T,F]
    swiglu_kernel<<<(TOKENS * (FFN / 8)) / 256, 256, 0, stream>>>(inter, act);
    // GEMM2: [T,F] x [H,F]^T -> out [T,H]       (M=2048/exp, N=2048, K=1408)
    gemm8p<FFN, HIDDEN, 8, float><<<8 * 8 * 8, 512, 0, stream>>>(act, w2T, out);
}